// Round 8
// baseline (78.436 us; speedup 1.0000x reference)
//
#include <hip/hip_runtime.h>
#include <math.h>

#define NB   4
#define SEQN 512
#define SEQM 512
#define QS   256   // Q_SIZE == K_SIZE
#define HH   128   // H
#define DV   256   // D_V
#define BM   (NB * SEQM)   // 2048 global k rows

static constexpr float kPreScale = 2.8853900817779268f;  // 2*log2(e)
static constexpr float kLog2e    = 1.4426950408889634f;

#if __has_builtin(__builtin_amdgcn_exp2f)
__device__ __forceinline__ float fexp2(float x) { return __builtin_amdgcn_exp2f(x); }
#else
__device__ __forceinline__ float fexp2(float x) { return exp2f(x); }
#endif

#if __has_builtin(__builtin_amdgcn_rcpf)
__device__ __forceinline__ float frcp(float x) { return __builtin_amdgcn_rcpf(x); }
#else
__device__ __forceinline__ float frcp(float x) { return 1.0f / x; }
#endif

// Fused q/k projection + tanh precompute.
// grid: 2 * 256 = 512 blocks, 512 threads (8 waves -> 4 waves/SIMD at 2 blk/CU).
// Block: 8 rows x 128 cols; thread: 2 rows.
// Q output (row-major): qt[row][ A_0..A_127 | wv_0*A_0 .. wv_127*A_127 ]
// K output (transposed, packed): kt[h][global_row] = float2(A, wv_h*A)
__global__ __launch_bounds__(512) void proj_kernel(
    const float* __restrict__ query, const float* __restrict__ key,
    const float* __restrict__ Wq, const float* __restrict__ Wk,
    const float* __restrict__ wv,
    float* __restrict__ qt, float2* __restrict__ kt) {
  const int t = threadIdx.x;
  const int half = (NB * SEQN) / 8;            // 256
  const bool isK = blockIdx.x >= half;
  const int rb   = isK ? (blockIdx.x - half) : blockIdx.x;
  const float* __restrict__ in = isK ? key : query;
  const float* __restrict__ W  = isK ? Wk  : Wq;
  const int row0 = rb * 8;

  const int j  = t & 127;                                      // output column (h)
  const int r0 = __builtin_amdgcn_readfirstlane((t >> 7) * 2); // wave-uniform -> SGPR

  // wave-uniform input rows -> scalar loads
  const float* __restrict__ x0p = in + (size_t)(row0 + r0 + 0) * QS;
  const float* __restrict__ x1p = in + (size_t)(row0 + r0 + 1) * QS;

  float a0 = 0.f, a1 = 0.f;
  for (int k0 = 0; k0 < QS; k0 += 4) {
    const float w0 = W[(k0 + 0) * HH + j];
    const float w1 = W[(k0 + 1) * HH + j];
    const float w2 = W[(k0 + 2) * HH + j];
    const float w3 = W[(k0 + 3) * HH + j];
    const float4 x0 = *reinterpret_cast<const float4*>(x0p + k0);  // s_load
    const float4 x1 = *reinterpret_cast<const float4*>(x1p + k0);
    a0 = fmaf(x0.x, w0, fmaf(x0.y, w1, fmaf(x0.z, w2, fmaf(x0.w, w3, a0))));
    a1 = fmaf(x1.x, w0, fmaf(x1.y, w1, fmaf(x1.z, w2, fmaf(x1.w, w3, a1))));
  }
  const float wvj = wv[j];
  float acc[2] = {a0, a1};
#pragma unroll
  for (int r = 0; r < 2; ++r) {
    const float e  = fexp2(acc[r] * kPreScale);          // e^{2x}
    const float rc = frcp(e + 1.0f);
    float A = fmaf(-2.0f, rc, 1.0f);                     // tanh(x)
    A = fminf(fmaxf(A, -0.99999988f), 0.99999988f);      // keep d = 1+AB > 0
    const int grow = row0 + r0 + r;
    if (isK) {
      kt[(size_t)j * BM + grow] = make_float2(A, wvj * A);
    } else {
      qt[(size_t)grow * (2 * HH) + j]      = A;
      qt[(size_t)grow * (2 * HH) + HH + j] = wvj * A;
    }
  }
}

// Fused scores + softmax + PV, h-split for full occupancy.
// grid = NB * (SEQN/4) = 512 blocks, 1024 threads (16 waves), ~40 KB LDS
// -> 2 blocks/CU x 16 waves = 32 waves/CU (100% nominal).
// Phase 1: thread (m = t&511, hh = t>>9) computes rational partial (N,D)
//          over its 64-h half for 4 query rows; zero transcendentals.
// Phase 1b: halves combine in LDS: N = N1*D2 + N2*D1, D = D1*D2.
// Phase 2: softmax, 4 waves per row.
// Phase 3: PV with 16 m-groups, two-step LDS combine (pvbuf aliases nd).
__global__ __launch_bounds__(1024) void fused_kernel(
    const float* __restrict__ qt, const float2* __restrict__ kt,
    const float* __restrict__ value, float* __restrict__ out) {
  __shared__ union SMem {
    float2 nd[2][4][SEQM];     // 32 KB: (N,D) partials per h-half
    float  pv[8][4][DV];       // 32 KB: PV m-group partials
  } u;
  __shared__ float sp[4][SEQM];  // 8 KB: scores then unnormalized p
  __shared__ float wred[32];     // wmax[0..15], wsum[16..31]

  const int t  = threadIdx.x;            // 0..1023
  const int b  = blockIdx.x >> 7;
  const int n0 = (blockIdx.x & 127) * 4;
  const int m  = t & 511;
  const int hbase = (t >> 9) * 64;       // h-half base

  const float* __restrict__ qb = qt + ((size_t)b * SEQN + n0) * (2 * HH);  // uniform
  const float2* __restrict__ kb = kt + (size_t)b * SEQM + m;               // coalesced

  float N[4], D[4];
#pragma unroll
  for (int n = 0; n < 4; ++n) { N[n] = 0.f; D[n] = 1.f; }

  for (int h0 = hbase; h0 < hbase + 64; h0 += 8) {
    float kA[8], kW[8];
#pragma unroll
    for (int jj = 0; jj < 8; ++jj) {
      const float2 f = kb[(size_t)(h0 + jj) * BM];   // 512B/wave, coalesced
      kA[jj] = f.x; kW[jj] = f.y;
    }
#pragma unroll
    for (int n = 0; n < 4; ++n) {
      const float* qr = qb + n * (2 * HH);
      const float4 a0 = *reinterpret_cast<const float4*>(qr + h0);           // s_load
      const float4 a1 = *reinterpret_cast<const float4*>(qr + h0 + 4);
      const float4 v0 = *reinterpret_cast<const float4*>(qr + HH + h0);
      const float4 v1 = *reinterpret_cast<const float4*>(qr + HH + h0 + 4);
      // s_i = wv*(A+B), d_i = 1 + A*B  (d in (0,2))
      const float s0 = v0.x + kW[0], d0 = fmaf(a0.x, kA[0], 1.0f);
      const float s1 = v0.y + kW[1], d1 = fmaf(a0.y, kA[1], 1.0f);
      const float s2 = v0.z + kW[2], d2 = fmaf(a0.z, kA[2], 1.0f);
      const float s3 = v0.w + kW[3], d3 = fmaf(a0.w, kA[3], 1.0f);
      const float s4 = v1.x + kW[4], d4 = fmaf(a1.x, kA[4], 1.0f);
      const float s5 = v1.y + kW[5], d5 = fmaf(a1.y, kA[5], 1.0f);
      const float s6 = v1.z + kW[6], d6 = fmaf(a1.z, kA[6], 1.0f);
      const float s7 = v1.w + kW[7], d7 = fmaf(a1.w, kA[7], 1.0f);
      // pairwise rational tree: sum s_i/d_i -> t07/e07
      const float t01 = fmaf(s0, d1, s1 * d0), e01 = d0 * d1;
      const float t23 = fmaf(s2, d3, s3 * d2), e23 = d2 * d3;
      const float t45 = fmaf(s4, d5, s5 * d4), e45 = d4 * d5;
      const float t67 = fmaf(s6, d7, s7 * d6), e67 = d6 * d7;
      const float t03 = fmaf(t01, e23, t23 * e01), e03 = e01 * e23;
      const float t47 = fmaf(t45, e67, t67 * e45), e47 = e45 * e67;
      const float t07 = fmaf(t03, e47, t47 * e03), e07 = e03 * e47;
      N[n] = fmaf(N[n], e07, t07 * D[n]);
      D[n] *= e07;
    }
  }
#pragma unroll
  for (int n = 0; n < 4; ++n) u.nd[t >> 9][n][m] = make_float2(N[n], D[n]);
  __syncthreads();

  // Phase 1b: rational combine of the two h-halves; 2 rows per thread.
  {
    const int nsel = (t >> 9) * 2;
#pragma unroll
    for (int k2 = 0; k2 < 2; ++k2) {
      const int n = nsel + k2;
      const float2 f1 = u.nd[0][n][m];
      const float2 f2 = u.nd[1][n][m];
      const float Nt = fmaf(f1.x, f2.y, f2.x * f1.y);
      const float Dt = f1.y * f2.y;
      sp[n][m] = Nt * frcp(Dt);
    }
  }
  __syncthreads();

  // Phase 2: softmax over m. 16 waves: row = wave&3, quarter = wave>>2.
  const int wave = t >> 6;
  const int lane = t & 63;
  const int row  = wave & 3;
  const int qtr  = wave >> 2;
  const int sbase = qtr * 128 + lane;
  float v0 = sp[row][sbase];
  float v1 = sp[row][sbase + 64];
  float mx = fmaxf(v0, v1);
#pragma unroll
  for (int off = 32; off > 0; off >>= 1) mx = fmaxf(mx, __shfl_xor(mx, off));
  if (lane == 0) wred[wave] = mx;
  __syncthreads();
  mx = fmaxf(fmaxf(wred[row], wred[row + 4]), fmaxf(wred[row + 8], wred[row + 12]));
  const float p0 = fexp2((v0 - mx) * kLog2e);
  const float p1 = fexp2((v1 - mx) * kLog2e);
  sp[row][sbase]      = p0;
  sp[row][sbase + 64] = p1;
  float sum = p0 + p1;
#pragma unroll
  for (int off = 32; off > 0; off >>= 1) sum += __shfl_xor(sum, off);
  if (lane == 0) wred[16 + wave] = sum;
  __syncthreads();

  // Phase 3: PV. mg = t>>6 (16 groups x 32 m), dq = (t&63)*4.
  const float* __restrict__ vb = value + (size_t)b * SEQM * DV;
  const int dq = (t & 63) * 4;
  const int mg = t >> 6;
  float o[4][4];
#pragma unroll
  for (int n = 0; n < 4; ++n)
#pragma unroll
    for (int jj = 0; jj < 4; ++jj) o[n][jj] = 0.f;
  const int mbeg = mg * 32;
  for (int mi = 0; mi < 32; mi += 4) {
    const int m0 = mbeg + mi;
    const float4 vv0 = *reinterpret_cast<const float4*>(vb + (size_t)(m0 + 0) * DV + dq);
    const float4 vv1 = *reinterpret_cast<const float4*>(vb + (size_t)(m0 + 1) * DV + dq);
    const float4 vv2 = *reinterpret_cast<const float4*>(vb + (size_t)(m0 + 2) * DV + dq);
    const float4 vv3 = *reinterpret_cast<const float4*>(vb + (size_t)(m0 + 3) * DV + dq);
#pragma unroll
    for (int n = 0; n < 4; ++n) {
      const float4 p4 = *reinterpret_cast<const float4*>(&sp[n][m0]);  // broadcast
      o[n][0] = fmaf(p4.x, vv0.x, fmaf(p4.y, vv1.x, fmaf(p4.z, vv2.x, fmaf(p4.w, vv3.x, o[n][0]))));
      o[n][1] = fmaf(p4.x, vv0.y, fmaf(p4.y, vv1.y, fmaf(p4.z, vv2.y, fmaf(p4.w, vv3.y, o[n][1]))));
      o[n][2] = fmaf(p4.x, vv0.z, fmaf(p4.y, vv1.z, fmaf(p4.z, vv2.z, fmaf(p4.w, vv3.z, o[n][2]))));
      o[n][3] = fmaf(p4.x, vv0.w, fmaf(p4.y, vv1.w, fmaf(p4.z, vv2.w, fmaf(p4.w, vv3.w, o[n][3]))));
    }
  }
  if (mg >= 8) {
#pragma unroll
    for (int n = 0; n < 4; ++n)
      *reinterpret_cast<float4*>(&u.pv[mg - 8][n][dq]) =
          make_float4(o[n][0], o[n][1], o[n][2], o[n][3]);
  }
  __syncthreads();
  if (mg < 8) {
#pragma unroll
    for (int n = 0; n < 4; ++n) {
      float4 prev = *reinterpret_cast<const float4*>(&u.pv[mg][n][dq]);
      prev.x += o[n][0]; prev.y += o[n][1]; prev.z += o[n][2]; prev.w += o[n][3];
      *reinterpret_cast<float4*>(&u.pv[mg][n][dq]) = prev;
    }
  }
  __syncthreads();

  // Final: n = t>>8, d = t&255 -> one output element per thread.
  {
    const int n = t >> 8;
    const int d = t & 255;
    const float rsn = frcp(wred[16 + n] + wred[20 + n] + wred[24 + n] + wred[28 + n]);
    float acc = 0.f;
#pragma unroll
    for (int g = 0; g < 8; ++g) acc += u.pv[g][n][d];
    out[((size_t)b * SEQN + n0 + n) * DV + d] = acc * rsn;
  }
}

extern "C" void kernel_launch(void* const* d_in, const int* in_sizes, int n_in,
                              void* d_out, int out_size, void* d_ws, size_t ws_size,
                              hipStream_t stream) {
  const float* query = (const float*)d_in[0];   // (4,512,256)
  const float* key   = (const float*)d_in[1];   // (4,512,256)
  const float* value = (const float*)d_in[2];   // (4,512,256)
  const float* W_q   = (const float*)d_in[3];   // (256,128)
  const float* W_k   = (const float*)d_in[4];   // (256,128)
  const float* W_v   = (const float*)d_in[5];   // (128,)
  float* out = (float*)d_out;                   // (4,512,256) f32

  // qt parks in d_out (2 MB): fused block (b,n0) reads only its OWN 4 q-rows
  // in phase 1 and overwrites exactly those rows at the end -> no hazard.
  float*  qt = (float*)d_out;                   // (2048, 256) [A | wv*A]
  float2* kt = (float2*)d_ws;                   // (128, 2048) float2(A, wv*A), 2 MB

  proj_kernel<<<2 * (NB * SEQN) / 8, 512, 0, stream>>>(query, key, W_q, W_k, W_v, qt, kt);
  fused_kernel<<<NB * (SEQN / 4), 1024, 0, stream>>>(qt, kt, value, out);
}

// Round 9
// 54.733 us; speedup vs baseline: 1.4331x; 1.4331x over previous
//
#include <hip/hip_runtime.h>
#include <math.h>

#define NB   4
#define SEQN 512
#define SEQM 512
#define QS   256   // Q_SIZE == K_SIZE
#define HH   128   // H
#define DV   256   // D_V
#define BM   (NB * SEQM)   // 2048 global k rows

static constexpr float kPreScale = 2.8853900817779268f;  // 2*log2(e)
static constexpr float kLog2e    = 1.4426950408889634f;

#if __has_builtin(__builtin_amdgcn_exp2f)
__device__ __forceinline__ float fexp2(float x) { return __builtin_amdgcn_exp2f(x); }
#else
__device__ __forceinline__ float fexp2(float x) { return exp2f(x); }
#endif

#if __has_builtin(__builtin_amdgcn_rcpf)
__device__ __forceinline__ float frcp(float x) { return __builtin_amdgcn_rcpf(x); }
#else
__device__ __forceinline__ float frcp(float x) { return 1.0f / x; }
#endif

// Fused q/k projection + tanh precompute.
// grid: 2 * 256 = 512 blocks, 512 threads. Block: 8 rows x 128 cols; thread: 2 rows.
// Q output (row-major): qt[row][ A_0..A_127 | wv_0*A_0 .. wv_127*A_127 ]
// K output (transposed, packed): kt[h][global_row] = float2(A, wv_h*A)
__global__ __launch_bounds__(512) void proj_kernel(
    const float* __restrict__ query, const float* __restrict__ key,
    const float* __restrict__ Wq, const float* __restrict__ Wk,
    const float* __restrict__ wv,
    float* __restrict__ qt, float2* __restrict__ kt) {
  const int t = threadIdx.x;
  const int half = (NB * SEQN) / 8;            // 256
  const bool isK = blockIdx.x >= half;
  const int rb   = isK ? (blockIdx.x - half) : blockIdx.x;
  const float* __restrict__ in = isK ? key : query;
  const float* __restrict__ W  = isK ? Wk  : Wq;
  const int row0 = rb * 8;

  const int j  = t & 127;                                      // output column (h)
  const int r0 = __builtin_amdgcn_readfirstlane((t >> 7) * 2); // wave-uniform -> SGPR

  // wave-uniform input rows -> scalar loads
  const float* __restrict__ x0p = in + (size_t)(row0 + r0 + 0) * QS;
  const float* __restrict__ x1p = in + (size_t)(row0 + r0 + 1) * QS;

  float a0 = 0.f, a1 = 0.f;
  for (int k0 = 0; k0 < QS; k0 += 4) {
    const float w0 = W[(k0 + 0) * HH + j];
    const float w1 = W[(k0 + 1) * HH + j];
    const float w2 = W[(k0 + 2) * HH + j];
    const float w3 = W[(k0 + 3) * HH + j];
    const float4 x0 = *reinterpret_cast<const float4*>(x0p + k0);  // s_load
    const float4 x1 = *reinterpret_cast<const float4*>(x1p + k0);
    a0 = fmaf(x0.x, w0, fmaf(x0.y, w1, fmaf(x0.z, w2, fmaf(x0.w, w3, a0))));
    a1 = fmaf(x1.x, w0, fmaf(x1.y, w1, fmaf(x1.z, w2, fmaf(x1.w, w3, a1))));
  }
  const float wvj = wv[j];
  float acc[2] = {a0, a1};
#pragma unroll
  for (int r = 0; r < 2; ++r) {
    const float e  = fexp2(acc[r] * kPreScale);          // e^{2x}
    const float rc = frcp(e + 1.0f);
    float A = fmaf(-2.0f, rc, 1.0f);                     // tanh(x)
    A = fminf(fmaxf(A, -0.99999988f), 0.99999988f);      // keep d = 1+AB > 0
    const int grow = row0 + r0 + r;
    if (isK) {
      kt[(size_t)j * BM + grow] = make_float2(A, wvj * A);
    } else {
      qt[(size_t)grow * (2 * HH) + j]      = A;
      qt[(size_t)grow * (2 * HH) + HH + j] = wvj * A;
    }
  }
}

// Fused scores + softmax + PV, h-split for full occupancy.
// grid = NB * (SEQN/4) = 512 blocks, 1024 threads (16 waves), ~40 KB LDS
// -> 2 blocks/CU x 16 waves = 32 waves/CU (100% nominal).
// Phase 1: thread (m = t&511, h-half = t>>9, SGPR-forced) computes rational
//          partial (N,D) over its 64-h half for 4 query rows.
// Phase 1b: halves combine in LDS: N = N1*D2 + N2*D1, D = D1*D2.
// Phase 2: softmax, 4 waves per row.
// Phase 3: PV with 16 m-groups, two-step LDS combine (pvbuf aliases nd).
__global__ __launch_bounds__(1024) void fused_kernel(
    const float* __restrict__ qt, const float2* __restrict__ kt,
    const float* __restrict__ value, float* __restrict__ out) {
  __shared__ union SMem {
    float2 nd[2][4][SEQM];     // 32 KB: (N,D) partials per h-half
    float  pv[8][4][DV];       // 32 KB: PV m-group partials
  } u;
  __shared__ float sp[4][SEQM];  // 8 KB: scores then unnormalized p
  __shared__ float wred[32];     // wmax[0..15], wsum[16..31]

  const int t  = threadIdx.x;            // 0..1023
  const int b  = blockIdx.x >> 7;
  const int n0 = (blockIdx.x & 127) * 4;
  const int m  = t & 511;
  // Wave-uniform (waves never straddle t=512): force into SGPR so all
  // q-loads below stay on the scalar (s_load) path.  <-- R8 regression fix
  const int hbase = __builtin_amdgcn_readfirstlane((t >> 9) * 64);

  const float* __restrict__ qb = qt + ((size_t)b * SEQN + n0) * (2 * HH);  // uniform
  const float2* __restrict__ kb = kt + (size_t)b * SEQM + m;               // coalesced

  float N[4], D[4];
#pragma unroll
  for (int n = 0; n < 4; ++n) { N[n] = 0.f; D[n] = 1.f; }

  for (int h0 = hbase; h0 < hbase + 64; h0 += 8) {
    float kA[8], kW[8];
#pragma unroll
    for (int jj = 0; jj < 8; ++jj) {
      const float2 f = kb[(size_t)(h0 + jj) * BM];   // 512B/wave, coalesced
      kA[jj] = f.x; kW[jj] = f.y;
    }
#pragma unroll
    for (int n = 0; n < 4; ++n) {
      const float* qr = qb + n * (2 * HH);
      const float4 a0 = *reinterpret_cast<const float4*>(qr + h0);           // s_load
      const float4 a1 = *reinterpret_cast<const float4*>(qr + h0 + 4);
      const float4 v0 = *reinterpret_cast<const float4*>(qr + HH + h0);
      const float4 v1 = *reinterpret_cast<const float4*>(qr + HH + h0 + 4);
      // s_i = wv*(A+B), d_i = 1 + A*B  (d in (0,2))
      const float s0 = v0.x + kW[0], d0 = fmaf(a0.x, kA[0], 1.0f);
      const float s1 = v0.y + kW[1], d1 = fmaf(a0.y, kA[1], 1.0f);
      const float s2 = v0.z + kW[2], d2 = fmaf(a0.z, kA[2], 1.0f);
      const float s3 = v0.w + kW[3], d3 = fmaf(a0.w, kA[3], 1.0f);
      const float s4 = v1.x + kW[4], d4 = fmaf(a1.x, kA[4], 1.0f);
      const float s5 = v1.y + kW[5], d5 = fmaf(a1.y, kA[5], 1.0f);
      const float s6 = v1.z + kW[6], d6 = fmaf(a1.z, kA[6], 1.0f);
      const float s7 = v1.w + kW[7], d7 = fmaf(a1.w, kA[7], 1.0f);
      // pairwise rational tree: sum s_i/d_i -> t07/e07
      const float t01 = fmaf(s0, d1, s1 * d0), e01 = d0 * d1;
      const float t23 = fmaf(s2, d3, s3 * d2), e23 = d2 * d3;
      const float t45 = fmaf(s4, d5, s5 * d4), e45 = d4 * d5;
      const float t67 = fmaf(s6, d7, s7 * d6), e67 = d6 * d7;
      const float t03 = fmaf(t01, e23, t23 * e01), e03 = e01 * e23;
      const float t47 = fmaf(t45, e67, t67 * e45), e47 = e45 * e67;
      const float t07 = fmaf(t03, e47, t47 * e03), e07 = e03 * e47;
      N[n] = fmaf(N[n], e07, t07 * D[n]);
      D[n] *= e07;
    }
  }
#pragma unroll
  for (int n = 0; n < 4; ++n) u.nd[t >> 9][n][m] = make_float2(N[n], D[n]);
  __syncthreads();

  // Phase 1b: rational combine of the two h-halves; 2 rows per thread.
  {
    const int nsel = (t >> 9) * 2;
#pragma unroll
    for (int k2 = 0; k2 < 2; ++k2) {
      const int n = nsel + k2;
      const float2 f1 = u.nd[0][n][m];
      const float2 f2 = u.nd[1][n][m];
      const float Nt = fmaf(f1.x, f2.y, f2.x * f1.y);
      const float Dt = f1.y * f2.y;
      sp[n][m] = Nt * frcp(Dt);
    }
  }
  __syncthreads();

  // Phase 2: softmax over m. 16 waves: row = wave&3, quarter = wave>>2.
  const int wave = t >> 6;
  const int lane = t & 63;
  const int row  = wave & 3;
  const int qtr  = wave >> 2;
  const int sbase = qtr * 128 + lane;
  float v0 = sp[row][sbase];
  float v1 = sp[row][sbase + 64];
  float mx = fmaxf(v0, v1);
#pragma unroll
  for (int off = 32; off > 0; off >>= 1) mx = fmaxf(mx, __shfl_xor(mx, off));
  if (lane == 0) wred[wave] = mx;
  __syncthreads();
  mx = fmaxf(fmaxf(wred[row], wred[row + 4]), fmaxf(wred[row + 8], wred[row + 12]));
  const float p0 = fexp2((v0 - mx) * kLog2e);
  const float p1 = fexp2((v1 - mx) * kLog2e);
  sp[row][sbase]      = p0;
  sp[row][sbase + 64] = p1;
  float sum = p0 + p1;
#pragma unroll
  for (int off = 32; off > 0; off >>= 1) sum += __shfl_xor(sum, off);
  if (lane == 0) wred[16 + wave] = sum;
  __syncthreads();

  // Phase 3: PV. mg = t>>6 (16 groups x 32 m), dq = (t&63)*4.
  const float* __restrict__ vb = value + (size_t)b * SEQM * DV;
  const int dq = (t & 63) * 4;
  const int mg = t >> 6;
  float o[4][4];
#pragma unroll
  for (int n = 0; n < 4; ++n)
#pragma unroll
    for (int jj = 0; jj < 4; ++jj) o[n][jj] = 0.f;
  const int mbeg = mg * 32;
  for (int mi = 0; mi < 32; mi += 4) {
    const int m0 = mbeg + mi;
    const float4 vv0 = *reinterpret_cast<const float4*>(vb + (size_t)(m0 + 0) * DV + dq);
    const float4 vv1 = *reinterpret_cast<const float4*>(vb + (size_t)(m0 + 1) * DV + dq);
    const float4 vv2 = *reinterpret_cast<const float4*>(vb + (size_t)(m0 + 2) * DV + dq);
    const float4 vv3 = *reinterpret_cast<const float4*>(vb + (size_t)(m0 + 3) * DV + dq);
#pragma unroll
    for (int n = 0; n < 4; ++n) {
      const float4 p4 = *reinterpret_cast<const float4*>(&sp[n][m0]);  // broadcast
      o[n][0] = fmaf(p4.x, vv0.x, fmaf(p4.y, vv1.x, fmaf(p4.z, vv2.x, fmaf(p4.w, vv3.x, o[n][0]))));
      o[n][1] = fmaf(p4.x, vv0.y, fmaf(p4.y, vv1.y, fmaf(p4.z, vv2.y, fmaf(p4.w, vv3.y, o[n][1]))));
      o[n][2] = fmaf(p4.x, vv0.z, fmaf(p4.y, vv1.z, fmaf(p4.z, vv2.z, fmaf(p4.w, vv3.z, o[n][2]))));
      o[n][3] = fmaf(p4.x, vv0.w, fmaf(p4.y, vv1.w, fmaf(p4.z, vv2.w, fmaf(p4.w, vv3.w, o[n][3]))));
    }
  }
  if (mg >= 8) {
#pragma unroll
    for (int n = 0; n < 4; ++n)
      *reinterpret_cast<float4*>(&u.pv[mg - 8][n][dq]) =
          make_float4(o[n][0], o[n][1], o[n][2], o[n][3]);
  }
  __syncthreads();
  if (mg < 8) {
#pragma unroll
    for (int n = 0; n < 4; ++n) {
      float4 prev = *reinterpret_cast<const float4*>(&u.pv[mg][n][dq]);
      prev.x += o[n][0]; prev.y += o[n][1]; prev.z += o[n][2]; prev.w += o[n][3];
      *reinterpret_cast<float4*>(&u.pv[mg][n][dq]) = prev;
    }
  }
  __syncthreads();

  // Final: n = t>>8, d = t&255 -> one output element per thread.
  {
    const int n = t >> 8;
    const int d = t & 255;
    const float rsn = frcp(wred[16 + n] + wred[20 + n] + wred[24 + n] + wred[28 + n]);
    float acc = 0.f;
#pragma unroll
    for (int g = 0; g < 8; ++g) acc += u.pv[g][n][d];
    out[((size_t)b * SEQN + n0 + n) * DV + d] = acc * rsn;
  }
}

extern "C" void kernel_launch(void* const* d_in, const int* in_sizes, int n_in,
                              void* d_out, int out_size, void* d_ws, size_t ws_size,
                              hipStream_t stream) {
  const float* query = (const float*)d_in[0];   // (4,512,256)
  const float* key   = (const float*)d_in[1];   // (4,512,256)
  const float* value = (const float*)d_in[2];   // (4,512,256)
  const float* W_q   = (const float*)d_in[3];   // (256,128)
  const float* W_k   = (const float*)d_in[4];   // (256,128)
  const float* W_v   = (const float*)d_in[5];   // (128,)
  float* out = (float*)d_out;                   // (4,512,256) f32

  // qt parks in d_out (2 MB): fused block (b,n0) reads only its OWN 4 q-rows
  // in phase 1 and overwrites exactly those rows at the end -> no hazard.
  float*  qt = (float*)d_out;                   // (2048, 256) [A | wv*A]
  float2* kt = (float2*)d_ws;                   // (128, 2048) float2(A, wv*A), 2 MB

  proj_kernel<<<2 * (NB * SEQN) / 8, 512, 0, stream>>>(query, key, W_q, W_k, W_v, qt, kt);
  fused_kernel<<<NB * (SEQN / 4), 1024, 0, stream>>>(qt, kt, value, out);
}

// Round 10
// 48.026 us; speedup vs baseline: 1.6332x; 1.1397x over previous
//
#include <hip/hip_runtime.h>
#include <math.h>

#define NB   4
#define SEQN 512
#define SEQM 512
#define QS   256   // Q_SIZE == K_SIZE
#define HH   128   // H
#define DV   256   // D_V
#define BM   (NB * SEQM)   // 2048 global k rows

static constexpr float kPreScale = 2.8853900817779268f;  // 2*log2(e)
static constexpr float kLog2e    = 1.4426950408889634f;

#if __has_builtin(__builtin_amdgcn_exp2f)
__device__ __forceinline__ float fexp2(float x) { return __builtin_amdgcn_exp2f(x); }
#else
__device__ __forceinline__ float fexp2(float x) { return exp2f(x); }
#endif

#if __has_builtin(__builtin_amdgcn_rcpf)
__device__ __forceinline__ float frcp(float x) { return __builtin_amdgcn_rcpf(x); }
#else
__device__ __forceinline__ float frcp(float x) { return 1.0f / x; }
#endif

// Fused q/k projection + tanh precompute (unchanged from R9).
// grid: 512 blocks, 512 threads. Block: 8 rows x 128 cols; thread: 2 rows.
__global__ __launch_bounds__(512) void proj_kernel(
    const float* __restrict__ query, const float* __restrict__ key,
    const float* __restrict__ Wq, const float* __restrict__ Wk,
    const float* __restrict__ wv,
    float* __restrict__ qt, float2* __restrict__ kt) {
  const int t = threadIdx.x;
  const int half = (NB * SEQN) / 8;            // 256
  const bool isK = blockIdx.x >= half;
  const int rb   = isK ? (blockIdx.x - half) : blockIdx.x;
  const float* __restrict__ in = isK ? key : query;
  const float* __restrict__ W  = isK ? Wk  : Wq;
  const int row0 = rb * 8;

  const int j  = t & 127;                                      // output column (h)
  const int r0 = __builtin_amdgcn_readfirstlane((t >> 7) * 2); // wave-uniform -> SGPR

  const float* __restrict__ x0p = in + (size_t)(row0 + r0 + 0) * QS;
  const float* __restrict__ x1p = in + (size_t)(row0 + r0 + 1) * QS;

  float a0 = 0.f, a1 = 0.f;
  for (int k0 = 0; k0 < QS; k0 += 4) {
    const float w0 = W[(k0 + 0) * HH + j];
    const float w1 = W[(k0 + 1) * HH + j];
    const float w2 = W[(k0 + 2) * HH + j];
    const float w3 = W[(k0 + 3) * HH + j];
    const float4 x0 = *reinterpret_cast<const float4*>(x0p + k0);  // s_load
    const float4 x1 = *reinterpret_cast<const float4*>(x1p + k0);
    a0 = fmaf(x0.x, w0, fmaf(x0.y, w1, fmaf(x0.z, w2, fmaf(x0.w, w3, a0))));
    a1 = fmaf(x1.x, w0, fmaf(x1.y, w1, fmaf(x1.z, w2, fmaf(x1.w, w3, a1))));
  }
  const float wvj = wv[j];
  float acc[2] = {a0, a1};
#pragma unroll
  for (int r = 0; r < 2; ++r) {
    const float e  = fexp2(acc[r] * kPreScale);          // e^{2x}
    const float rc = frcp(e + 1.0f);
    float A = fmaf(-2.0f, rc, 1.0f);                     // tanh(x)
    A = fminf(fmaxf(A, -0.99999988f), 0.99999988f);      // keep d = 1+AB > 0
    const int grow = row0 + r0 + r;
    if (isK) {
      kt[(size_t)j * BM + grow] = make_float2(A, wvj * A);
    } else {
      qt[(size_t)grow * (2 * HH) + j]      = A;
      qt[(size_t)grow * (2 * HH) + HH + j] = wvj * A;
    }
  }
}

// Fused scores + softmax + PV, TN=8 via n-split.
// grid = NB * (SEQN/8) = 256 blocks (1/CU), 1024 threads (16 waves), 48 KB LDS.
// Phase 1: thread (m = t&511, row-quad = t>>9) computes 4 scores via the
//          tanh-identity rational tree; k-chunks register-double-buffered.
// Phase 2: in-wave full-row softmax (no cross-wave combine).
// Phase 3: PV, 8 m-groups x float2 d-pairs; 4-buffer two-step LDS combine.
__global__ __launch_bounds__(1024) void fused_kernel(
    const float* __restrict__ qt, const float2* __restrict__ kt,
    const float* __restrict__ value, float* __restrict__ out) {
  __shared__ float sp[8][SEQM];        // 16 KB: scores then unnormalized p
  __shared__ float pvbuf[4][8][DV];    // 32 KB: PV partial buffers
  __shared__ float rsh[8];             // 1/rowsum

  const int t  = threadIdx.x;            // 0..1023
  const int b  = blockIdx.x >> 6;        // 4 batches x 64 tiles
  const int n0 = (blockIdx.x & 63) * 8;
  const int m  = t & 511;
  // Wave-uniform row-quad base (waves never straddle t=512) -> SGPR q-loads.
  const int nq4 = __builtin_amdgcn_readfirstlane((t >> 9) * 4);

  const float* __restrict__ qb = qt + ((size_t)b * SEQN + n0 + nq4) * (2 * HH);
  const float2* __restrict__ kb = kt + (size_t)b * SEQM + m;   // coalesced

  float N[4], D[4];
#pragma unroll
  for (int n = 0; n < 4; ++n) { N[n] = 0.f; D[n] = 1.f; }

  // register double-buffer: prefetch chunk 0
  float2 fb[8];
#pragma unroll
  for (int jj = 0; jj < 8; ++jj) fb[jj] = kb[(size_t)jj * BM];

  for (int h0 = 0; h0 < HH; h0 += 8) {
    float kA[8], kW[8];
#pragma unroll
    for (int jj = 0; jj < 8; ++jj) { kA[jj] = fb[jj].x; kW[jj] = fb[jj].y; }
    if (h0 + 8 < HH) {
#pragma unroll
      for (int jj = 0; jj < 8; ++jj) fb[jj] = kb[(size_t)(h0 + 8 + jj) * BM];
    }
#pragma unroll
    for (int n = 0; n < 4; ++n) {
      const float* qr = qb + n * (2 * HH);
      const float4 a0 = *reinterpret_cast<const float4*>(qr + h0);           // s_load
      const float4 a1 = *reinterpret_cast<const float4*>(qr + h0 + 4);
      const float4 v0 = *reinterpret_cast<const float4*>(qr + HH + h0);
      const float4 v1 = *reinterpret_cast<const float4*>(qr + HH + h0 + 4);
      // s_i = wv*(A+B), d_i = 1 + A*B  (d in (0,2))
      const float s0 = v0.x + kW[0], d0 = fmaf(a0.x, kA[0], 1.0f);
      const float s1 = v0.y + kW[1], d1 = fmaf(a0.y, kA[1], 1.0f);
      const float s2 = v0.z + kW[2], d2 = fmaf(a0.z, kA[2], 1.0f);
      const float s3 = v0.w + kW[3], d3 = fmaf(a0.w, kA[3], 1.0f);
      const float s4 = v1.x + kW[4], d4 = fmaf(a1.x, kA[4], 1.0f);
      const float s5 = v1.y + kW[5], d5 = fmaf(a1.y, kA[5], 1.0f);
      const float s6 = v1.z + kW[6], d6 = fmaf(a1.z, kA[6], 1.0f);
      const float s7 = v1.w + kW[7], d7 = fmaf(a1.w, kA[7], 1.0f);
      // pairwise rational tree: sum s_i/d_i -> t07/e07
      const float t01 = fmaf(s0, d1, s1 * d0), e01 = d0 * d1;
      const float t23 = fmaf(s2, d3, s3 * d2), e23 = d2 * d3;
      const float t45 = fmaf(s4, d5, s5 * d4), e45 = d4 * d5;
      const float t67 = fmaf(s6, d7, s7 * d6), e67 = d6 * d7;
      const float t03 = fmaf(t01, e23, t23 * e01), e03 = e01 * e23;
      const float t47 = fmaf(t45, e67, t67 * e45), e47 = e45 * e67;
      const float t07 = fmaf(t03, e47, t47 * e03), e07 = e03 * e47;
      N[n] = fmaf(N[n], e07, t07 * D[n]);
      D[n] *= e07;
    }
  }
#pragma unroll
  for (int n = 0; n < 4; ++n) sp[nq4 + n][m] = N[n] * frcp(D[n]);
  __syncthreads();

  // Phase 2: in-wave full-row softmax. wave w: row = w>>1, half = w&1.
  const int wave = t >> 6;
  const int lane = t & 63;
  const int row  = wave >> 1;
  const int hf   = wave & 1;
  float v[8];
  float mx = -1e30f;
#pragma unroll
  for (int i = 0; i < 8; ++i) {
    v[i] = sp[row][lane + 64 * i];     // full row, 8 vals/lane
    mx = fmaxf(mx, v[i]);
  }
#pragma unroll
  for (int off = 32; off > 0; off >>= 1) mx = fmaxf(mx, __shfl_xor(mx, off));
  float p[8];
  float sum = 0.f;
#pragma unroll
  for (int i = 0; i < 8; ++i) {
    p[i] = fexp2((v[i] - mx) * kLog2e);
    sum += p[i];
  }
#pragma unroll
  for (int off = 32; off > 0; off >>= 1) sum += __shfl_xor(sum, off);
  __syncthreads();                      // all row reads done before overwrite
#pragma unroll
  for (int i = 4 * hf; i < 4 * hf + 4; ++i) sp[row][lane + 64 * i] = p[i];
  if (hf == 0 && lane == 0) rsh[row] = frcp(sum);
  __syncthreads();

  // Phase 3: PV. mg = t>>7 (8 groups x 64 m), dp = (t&127)*2 (float2 d-pair).
  const float* __restrict__ vb = value + (size_t)b * SEQM * DV;
  const int dp = (t & 127) * 2;
  const int mg = t >> 7;
  float o[8][2];
#pragma unroll
  for (int n = 0; n < 8; ++n) { o[n][0] = 0.f; o[n][1] = 0.f; }
  const int mbeg = mg * 64;
  for (int mi = 0; mi < 64; mi += 4) {
    const int m0 = mbeg + mi;
    const float2 w0 = *reinterpret_cast<const float2*>(vb + (size_t)(m0 + 0) * DV + dp);
    const float2 w1 = *reinterpret_cast<const float2*>(vb + (size_t)(m0 + 1) * DV + dp);
    const float2 w2 = *reinterpret_cast<const float2*>(vb + (size_t)(m0 + 2) * DV + dp);
    const float2 w3 = *reinterpret_cast<const float2*>(vb + (size_t)(m0 + 3) * DV + dp);
#pragma unroll
    for (int n = 0; n < 8; ++n) {
      const float4 p4 = *reinterpret_cast<const float4*>(&sp[n][m0]);  // broadcast
      o[n][0] = fmaf(p4.x, w0.x, fmaf(p4.y, w1.x, fmaf(p4.z, w2.x, fmaf(p4.w, w3.x, o[n][0]))));
      o[n][1] = fmaf(p4.x, w0.y, fmaf(p4.y, w1.y, fmaf(p4.z, w2.y, fmaf(p4.w, w3.y, o[n][1]))));
    }
  }
  if (mg >= 4) {
#pragma unroll
    for (int n = 0; n < 8; ++n)
      *reinterpret_cast<float2*>(&pvbuf[mg - 4][n][dp]) = make_float2(o[n][0], o[n][1]);
  }
  __syncthreads();
  if (mg < 4) {
#pragma unroll
    for (int n = 0; n < 8; ++n) {
      float2 prev = *reinterpret_cast<const float2*>(&pvbuf[mg][n][dp]);
      prev.x += o[n][0]; prev.y += o[n][1];
      *reinterpret_cast<float2*>(&pvbuf[mg][n][dp]) = prev;
    }
  }
  __syncthreads();

  // Final: n = t>>7, d = t&127 (and d+128): 2 outputs/thread.
  {
    const int n = t >> 7;
    const int d = t & 127;
    const float rsn = rsh[n];
    float accA = 0.f, accB = 0.f;
#pragma unroll
    for (int g = 0; g < 4; ++g) {
      accA += pvbuf[g][n][d];
      accB += pvbuf[g][n][d + 128];
    }
    const size_t ob = ((size_t)b * SEQN + n0 + n) * DV;
    out[ob + d]       = accA * rsn;
    out[ob + d + 128] = accB * rsn;
  }
}

extern "C" void kernel_launch(void* const* d_in, const int* in_sizes, int n_in,
                              void* d_out, int out_size, void* d_ws, size_t ws_size,
                              hipStream_t stream) {
  const float* query = (const float*)d_in[0];   // (4,512,256)
  const float* key   = (const float*)d_in[1];   // (4,512,256)
  const float* value = (const float*)d_in[2];   // (4,512,256)
  const float* W_q   = (const float*)d_in[3];   // (256,128)
  const float* W_k   = (const float*)d_in[4];   // (256,128)
  const float* W_v   = (const float*)d_in[5];   // (128,)
  float* out = (float*)d_out;                   // (4,512,256) f32

  // qt parks in d_out (2 MB): fused block (b,n0) reads only its OWN 8 q-rows
  // in phase 1 and overwrites exactly those rows at the end -> no hazard.
  float*  qt = (float*)d_out;                   // (2048, 256) [A | wv*A]
  float2* kt = (float2*)d_ws;                   // (128, 2048) float2(A, wv*A), 2 MB

  proj_kernel<<<2 * (NB * SEQN) / 8, 512, 0, stream>>>(query, key, W_q, W_k, W_v, qt, kt);
  fused_kernel<<<NB * (SEQN / 8), 1024, 0, stream>>>(qt, kt, value, out);
}